// Round 10
// baseline (548.192 us; speedup 1.0000x reference)
//
#include <hip/hip_runtime.h>

// 2-layer LSTM (H=50) + FC head. Transposed-MFMA fp16, cross-layer pipelined.
// R10 = R9 with 7 fat waves instead of 13 thin ones:
//  - wave w<6 owns p-tiles {2w, 2w+1}; wave 6 owns tile 12 (+ x-feed lane).
//  - each wave reads h B-fragments ONCE for both its tiles -> LDS reads per
//    CU-phase drop 52 -> 28 ds_read_b128 (the 13-wave version read the SAME
//    fragments 13x). Barrier width 13 -> 7 waves.
//  - gates^T = W @ h^T; A = weights in registers, B = h in LDS frag layout;
//    gate rows permuted p = 4j+g -> one lane owns all 4 gates of a unit ->
//    cell update fully in-register; x + biases ride dead K-lanes (k=50: x,
//    k=51: 1.0/biases); activations division-free (v_rcp + v_exp2).
//  - phase p computes L1[p] + L2[p-1]; ONE barrier/phase (513 = minimum:
//    the recurrence needs a full h broadcast per step).
// B=4096, T=512. Grid 256 x 448 threads (7 waves), NB=16, 1 block/CU.
// R8 lesson: per-block work is batch-independent -> never split batch below
// NB=16/block. R3 lesson: launch_bounds must leave VGPR headroom (448,1).

#define HID 50
#define SEQ 512
#define NB 16
#define NTHREADS 448
#define XP 516            // xs row stride (floats)

typedef _Float16 f16x8 __attribute__((ext_vector_type(8)));
typedef float    f32x4 __attribute__((ext_vector_type(4)));

#define LOG2E 1.44269504f

__device__ __forceinline__ float sigf(float x) {
    return __builtin_amdgcn_rcpf(1.0f + __builtin_amdgcn_exp2f(x * -LOG2E));
}
__device__ __forceinline__ float tanh_fast(float x) {
    return 1.0f - 2.0f * __builtin_amdgcn_rcpf(
        1.0f + __builtin_amdgcn_exp2f(x * (2.0f * LOG2E)));
}
__device__ __forceinline__ float lstm_cell(const f32x4 g, float& c) {
    const float ii = sigf(g[0]);
    const float ff = sigf(g[1]);
    const float gg = tanh_fast(g[2]);
    const float oo = sigf(g[3]);
    c = ff * c + ii * gg;
    return oo * tanh_fast(c);
}

// h LDS layout: 16B chunk (kt*4+qh)*16 + m holds h[m][k = kt*32+qh*8+0..7].
// Reader (lane m=l15, quad qq, k-chunk kt) reads chunk (kt*4+qq)*16+m.
// Writer of h[m][j]: chunk ((j>>5)*4+((j>>3)&3))*16 + m, half j&7.
// j=50 -> chunk 96+m half 2 (x rides here), j=51 -> chunk 96+m half 3 (1.0).

__global__ __launch_bounds__(NTHREADS, 1)
void lstm2_fc_v10(const float* __restrict__ x,
                  const float* __restrict__ w_ih0,
                  const float* __restrict__ w_hh0,
                  const float* __restrict__ b_ih0,
                  const float* __restrict__ b_hh0,
                  const float* __restrict__ w_ih1,
                  const float* __restrict__ w_hh1,
                  const float* __restrict__ b_ih1,
                  const float* __restrict__ b_hh1,
                  const float* __restrict__ fc_w,
                  const float* __restrict__ fc_b,
                  float* __restrict__ out)
{
    __shared__ float xs[NB * XP];        // 33 KB  x for all 512 steps
    __shared__ f16x8 h1f[2][128];        //  4 KB  h1 double-buffered, frag layout
    __shared__ f16x8 h2f[2][128];        //  4 KB  h2 double-buffered

    const int tid = threadIdx.x;
    const int b0  = blockIdx.x * NB;
    const int w   = tid >> 6;            // wave id 0..6
    const int l15 = tid & 15;            // MFMA lane column (batch m)
    const int qq  = (tid >> 4) & 3;      // MFMA lane quad
    const bool fat = (w < 6);            // waves 0..5: 2 tiles; wave 6: 1 tile

    // ---- stage x into LDS (coalesced float4) ----
    for (int idx = tid; idx < NB * 128; idx += NTHREADS) {
        const int b  = idx >> 7;
        const int t4 = idx & 127;
        *(float4*)&xs[b * XP + t4 * 4] =
            *(const float4*)&x[(size_t)(b0 + b) * SEQ + t4 * 4];
    }
    if (tid < NB) {                       // zero x pad column t=512..515
        const float4 z = {0.f, 0.f, 0.f, 0.f};
        *(float4*)&xs[tid * XP + 512] = z;
    }
    // ---- zero h buffers ----
    if (tid < 256) {
        f16x8 z = {};
        h1f[tid >> 7][tid & 127] = z;
        h2f[tid >> 7][tid & 127] = z;
    }

    // ---- load weight A-fragments (one-time), gate rows permuted ----
    // lane holds W[p = T*16 + l15][k = kt*32 + qq*8 + j], n(p) = (p&3)*HID+(p>>2)
    // specials: mat0 k=50 -> w_ih0, k=51 -> biasL1; mat1 k=51 -> biasL2.
    const float* mats[3] = { w_hh0, w_ih1, w_hh1 };
    f16x8 wa[3][2][2];                   // [mat][tile][kt] = 12 frags = 48 VGPR
#pragma unroll
    for (int tt = 0; tt < 2; ++tt) {
        const int  T   = 2 * w + tt;
        const int  pA  = T * 16 + l15;
        const bool pok = (pA < 4 * HID);
        const int  n   = pok ? ((pA & 3) * HID + (pA >> 2)) : 0;
#pragma unroll
        for (int mi = 0; mi < 3; ++mi) {
#pragma unroll
            for (int kt = 0; kt < 2; ++kt) {
                f16x8 f;
#pragma unroll
                for (int j = 0; j < 8; ++j) {
                    const int k = kt * 32 + qq * 8 + j;
                    float v = 0.0f;
                    if (pok) {
                        if (k < HID)                     v = mats[mi][n * HID + k];
                        else if (mi == 0 && k == HID)    v = w_ih0[n];
                        else if (mi == 0 && k == HID+1)  v = b_ih0[n] + b_hh0[n];
                        else if (mi == 1 && k == HID+1)  v = b_ih1[n] + b_hh1[n];
                    }
                    f[j] = (_Float16)v;
                }
                wa[mi][tt][kt] = f;
            }
        }
    }

    // ---- per-lane invariants ----
    // tile tt owns unit ju = (2w+tt)*4 + qq; wave 6 tt=0: ju = 48..51.
    int wOff[2];
#pragma unroll
    for (int tt = 0; tt < 2; ++tt) {
        const int ju = (2 * w + tt) * 4 + qq;
        const int jc = ju & 63;          // wave6 tt=1 unused; keep in range
        wOff[tt] = ((((jc >> 5) * 4) + ((jc >> 3) & 3)) * 16 + l15) * 8 + (jc & 7);
    }
    const int rdo = qq * 16 + l15;       // B-frag chunk index, kt=0
    const float* xrow = xs + l15 * XP;   // x row for the x-lane (wave6 qq=2)

    float c1[2] = {0.f, 0.f};
    float c2[2] = {0.f, 0.f};

    __syncthreads();   // xs + zeros visible

    // ---- seed specials: h1f[0] k=50 = x[m][0]; k=51 = 1.0 in BOTH buffers.
    // The 1.0 lane (wave6 qq=3) never writes in-loop, so both stay valid.
    if (tid < NB) {
        _Float16* e0 = (_Float16*)&h1f[0][96 + tid];
        e0[2] = (_Float16)xs[tid * XP];
        e0[3] = (_Float16)1.0f;
        ((_Float16*)&h1f[1][96 + tid])[3] = (_Float16)1.0f;
    }
    __syncthreads();

    // ---- phase body: L1[p] (doL1) + L2[p-1] (doL2), one barrier ----
    auto phase = [&](const f16x8* __restrict__ h1o, const f16x8* __restrict__ h2o,
                     f16x8* __restrict__ h1n, f16x8* __restrict__ h2n,
                     int p, bool doL1, bool doL2) {
        const f16x8 hb0 = h1o[rdo];          // read ONCE, used by both tiles+layers
        const f16x8 hb1 = h1o[64 + rdo];
        _Float16 hw1[2], hw2[2];
        if (doL1) {
#pragma unroll
            for (int tt = 0; tt < 2; ++tt) {
                if (tt == 0 || fat) {
                    f32x4 acc = {0.f, 0.f, 0.f, 0.f};
                    acc = __builtin_amdgcn_mfma_f32_16x16x32_f16(wa[0][tt][0], hb0, acc, 0, 0, 0);
                    acc = __builtin_amdgcn_mfma_f32_16x16x32_f16(wa[0][tt][1], hb1, acc, 0, 0, 0);
                    hw1[tt] = (_Float16)lstm_cell(acc, c1[tt]);
                }
            }
        }
        if (doL2) {
            const f16x8 sb0 = h2o[rdo];
            const f16x8 sb1 = h2o[64 + rdo];
#pragma unroll
            for (int tt = 0; tt < 2; ++tt) {
                if (tt == 0 || fat) {
                    f32x4 acc = {0.f, 0.f, 0.f, 0.f};
                    acc = __builtin_amdgcn_mfma_f32_16x16x32_f16(wa[1][tt][0], hb0, acc, 0, 0, 0);
                    acc = __builtin_amdgcn_mfma_f32_16x16x32_f16(wa[1][tt][1], hb1, acc, 0, 0, 0);
                    acc = __builtin_amdgcn_mfma_f32_16x16x32_f16(wa[2][tt][0], sb0, acc, 0, 0, 0);
                    acc = __builtin_amdgcn_mfma_f32_16x16x32_f16(wa[2][tt][1], sb1, acc, 0, 0, 0);
                    hw2[tt] = (_Float16)lstm_cell(acc, c2[tt]);
                }
            }
        }
        if (doL1) {
            if (fat) {                            // wave-uniform branch
                ((_Float16*)h1n)[wOff[0]] = hw1[0];
                ((_Float16*)h1n)[wOff[1]] = hw1[1];
            } else {                              // wave 6: units 48,49 + x lane
                if (qq < 2)       ((_Float16*)h1n)[wOff[0]] = hw1[0];
                else if (qq == 2) ((_Float16*)h1n)[wOff[0]] =
                                      (_Float16)xrow[p + 1];
                /* qq == 3: the 1.0 lane, pre-seeded, never written */
            }
        }
        if (doL2) {
            if (fat) {
                ((_Float16*)h2n)[wOff[0]] = hw2[0];
                ((_Float16*)h2n)[wOff[1]] = hw2[1];
            } else if (qq < 2) {
                ((_Float16*)h2n)[wOff[0]] = hw2[0];
            }
        }
        __syncthreads();
    };

    // phase p reads buf[p&1], writes buf[1-(p&1)]
    phase(h1f[0], h2f[0], h1f[1], h2f[1], 0, true, false);      // L1[0]
#pragma unroll 1
    for (int p = 1; p <= 509; p += 2) {
        phase(h1f[1], h2f[1], h1f[0], h2f[0], p,     true, true);
        phase(h1f[0], h2f[0], h1f[1], h2f[1], p + 1, true, true);
    }
    phase(h1f[1], h2f[1], h1f[0], h2f[0], 511, true,  true);
    phase(h1f[0], h2f[0], h1f[1], h2f[1], 512, false, true);    // L2[511]
    // h2[511] now lives in h2f[1]

    // ============ FC head: out[b] = h2[T-1] . fc_w + fc_b ============
    if (tid < NB) {
        const int m = tid;
        const _Float16* h2e = (const _Float16*)h2f[1];
        float s = fc_b[0];
        for (int j = 0; j < HID; ++j) {
            const int chunk = (((j >> 5) * 4) + ((j >> 3) & 3)) * 16 + m;
            s += fc_w[j] * (float)h2e[chunk * 8 + (j & 7)];
        }
        out[b0 + m] = s;
    }
}

extern "C" void kernel_launch(void* const* d_in, const int* in_sizes, int n_in,
                              void* d_out, int out_size, void* d_ws, size_t ws_size,
                              hipStream_t stream) {
    const float* x     = (const float*)d_in[0];
    const float* w_ih0 = (const float*)d_in[1];
    const float* w_hh0 = (const float*)d_in[2];
    const float* b_ih0 = (const float*)d_in[3];
    const float* b_hh0 = (const float*)d_in[4];
    const float* w_ih1 = (const float*)d_in[5];
    const float* w_hh1 = (const float*)d_in[6];
    const float* b_ih1 = (const float*)d_in[7];
    const float* b_hh1 = (const float*)d_in[8];
    const float* fc_w  = (const float*)d_in[9];
    const float* fc_b  = (const float*)d_in[10];
    float* out = (float*)d_out;

    const int B = in_sizes[0] / SEQ;  // 4096

    lstm2_fc_v10<<<B / NB, NTHREADS, 0, stream>>>(
        x, w_ih0, w_hh0, b_ih0, b_hh0, w_ih1, w_hh1, b_ih1, b_hh1, fc_w, fc_b, out);
}

// Round 11
// 422.704 us; speedup vs baseline: 1.2969x; 1.2969x over previous
//
#include <hip/hip_runtime.h>

// 2-layer LSTM (H=50) + FC head. Transposed-MFMA fp16, cross-layer pipelined.
// R11 = R9 structure with the 26 (layer,tile) tasks spread over 16 waves
// (max block) instead of 13 pacer-weight waves:
//   waves 0..5 : L1 tiles {2w,2w+1}   (4 MFMA + 2 cells, read h1 only)
//   wave  6    : L1 tile 12 (+x-feed) (2 MFMA + 1 cell)
//   waves 7..10: L2 tiles {2i,2i+1}   (8 MFMA + 2 cells)  <- pacers
//   waves 11..15: L2 tile 8+i single  (4 MFMA + 1 cell)
// Per-SIMD issue drops from 3.25 full bodies (~845cyc) to 1 pacer + 3 light
// (~690cyc) and occupancy rises 13 -> 16 waves. Total work & numerics
// IDENTICAL to R9 -> absmax bit-identical.
// Everything else as R9: gates^T = W @ h^T (A = weights in regs, B = h in LDS
// frag layout); gate rows permuted p=4j+g -> cell fully in-register; x + all
// biases ride dead K-lanes (h1 k=50: x, k=51: 1.0); activations v_rcp+v_exp2;
// phase p = L1[p] + L2[p-1], ONE barrier/phase (513 = provable minimum).
// Lessons: R8/R10: wave count >> LDS redundancy; grid locked at 256 (NB=16).

#define HID 50
#define SEQ 512
#define NB 16
#define NTHREADS 1024
#define XP 516            // xs row stride (floats)

typedef _Float16 f16x8 __attribute__((ext_vector_type(8)));
typedef float    f32x4 __attribute__((ext_vector_type(4)));

#define LOG2E 1.44269504f

__device__ __forceinline__ float sigf(float x) {
    return __builtin_amdgcn_rcpf(1.0f + __builtin_amdgcn_exp2f(x * -LOG2E));
}
__device__ __forceinline__ float tanh_fast(float x) {
    return 1.0f - 2.0f * __builtin_amdgcn_rcpf(
        1.0f + __builtin_amdgcn_exp2f(x * (2.0f * LOG2E)));
}
__device__ __forceinline__ float lstm_cell(const f32x4 g, float& c) {
    const float ii = sigf(g[0]);
    const float ff = sigf(g[1]);
    const float gg = tanh_fast(g[2]);
    const float oo = sigf(g[3]);
    c = ff * c + ii * gg;
    return oo * tanh_fast(c);
}

// h LDS layout: 16B chunk (kt*4+qh)*16 + m holds h[m][k = kt*32+qh*8+0..7].
// Reader (lane m=l15, quad qq, k-chunk kt) reads chunk (kt*4+qq)*16+m.
// Writer of h[m][j]: chunk ((j>>5)*4+((j>>3)&3))*16 + m, half j&7.
// j=50 -> chunk 96+m half 2 (x rides here), j=51 -> chunk 96+m half 3 (1.0).

__global__ __launch_bounds__(NTHREADS)
void lstm2_fc_v11(const float* __restrict__ x,
                  const float* __restrict__ w_ih0,
                  const float* __restrict__ w_hh0,
                  const float* __restrict__ b_ih0,
                  const float* __restrict__ b_hh0,
                  const float* __restrict__ w_ih1,
                  const float* __restrict__ w_hh1,
                  const float* __restrict__ b_ih1,
                  const float* __restrict__ b_hh1,
                  const float* __restrict__ fc_w,
                  const float* __restrict__ fc_b,
                  float* __restrict__ out)
{
    __shared__ float xs[NB * XP];        // 33 KB  x for all 512 steps
    __shared__ f16x8 h1f[2][128];        //  4 KB  h1 double-buffered, frag layout
    __shared__ f16x8 h2f[2][128];        //  4 KB  h2 double-buffered

    const int tid = threadIdx.x;
    const int b0  = blockIdx.x * NB;
    const int w   = tid >> 6;            // wave id 0..15
    const int l15 = tid & 15;            // MFMA lane column (batch m)
    const int qq  = (tid >> 4) & 3;      // MFMA lane quad

    // ---- role / tile assignment (all wave-uniform) ----
    const bool isL1 = (w < 7);
    int T0, T1, nt;                      // tiles owned; nt in {1,2}
    if (isL1) {
        if (w < 6) { T0 = 2 * w;  T1 = 2 * w + 1; nt = 2; }
        else       { T0 = 12;     T1 = 12;        nt = 1; }
    } else {
        const int i = w - 7;
        if (i < 4) { T0 = 2 * i;  T1 = 2 * i + 1; nt = 2; }
        else       { T0 = 4 + i;  T1 = 4 + i;     nt = 1; }   // tiles 8..12
    }

    // ---- stage x into LDS (coalesced float4) ----
    for (int idx = tid; idx < NB * 128; idx += NTHREADS) {
        const int b  = idx >> 7;
        const int t4 = idx & 127;
        *(float4*)&xs[b * XP + t4 * 4] =
            *(const float4*)&x[(size_t)(b0 + b) * SEQ + t4 * 4];
    }
    if (tid < NB) {                       // zero x pad column t=512..515
        const float4 z = {0.f, 0.f, 0.f, 0.f};
        *(float4*)&xs[tid * XP + 512] = z;
    }
    // ---- zero h buffers ----
    if (tid < 256) {
        f16x8 z = {};
        h1f[tid >> 7][tid & 127] = z;
        h2f[tid >> 7][tid & 127] = z;
    }

    // ---- load weight A-fragments (one-time), gate rows permuted ----
    // L1 waves: mat w_hh0 (specials k=50 -> w_ih0, k=51 -> biasL1).
    // L2 waves: mats w_ih1 (special k=51 -> biasL2) and w_hh1.
    // lane holds W[p = T*16 + l15][k = kt*32 + qq*8 + j], n(p)=(p&3)*HID+(p>>2)
    f16x8 wA[2][2];                      // [tile][kt]  (L1: w_hh0 | L2: w_ih1)
    f16x8 wB[2][2];                      // [tile][kt]  (L2 only: w_hh1)
#pragma unroll
    for (int tt = 0; tt < 2; ++tt) {
        const int  T   = (tt == 0) ? T0 : T1;
        const int  pA  = T * 16 + l15;
        const bool pok = (pA < 4 * HID);
        const int  n   = pok ? ((pA & 3) * HID + (pA >> 2)) : 0;
#pragma unroll
        for (int kt = 0; kt < 2; ++kt) {
            f16x8 fa, fb;
#pragma unroll
            for (int j = 0; j < 8; ++j) {
                const int k = kt * 32 + qq * 8 + j;
                float va = 0.0f, vb = 0.0f;
                if (pok) {
                    if (isL1) {
                        if (k < HID)          va = w_hh0[n * HID + k];
                        else if (k == HID)    va = w_ih0[n];
                        else if (k == HID+1)  va = b_ih0[n] + b_hh0[n];
                    } else {
                        if (k < HID)        { va = w_ih1[n * HID + k];
                                              vb = w_hh1[n * HID + k]; }
                        else if (k == HID+1)  va = b_ih1[n] + b_hh1[n];
                    }
                }
                fa[j] = (_Float16)va;
                fb[j] = (_Float16)vb;
            }
            wA[tt][kt] = fa;
            wB[tt][kt] = fb;
        }
    }

    // ---- per-lane invariants ----
    int wOff[2];
#pragma unroll
    for (int tt = 0; tt < 2; ++tt) {
        const int ju = ((tt == 0) ? T0 : T1) * 4 + qq;     // <= 51
        wOff[tt] = ((((ju >> 5) * 4) + ((ju >> 3) & 3)) * 16 + l15) * 8 + (ju & 7);
    }
    const int rdo = qq * 16 + l15;       // B-frag chunk index, kt=0
    const float* xrow = xs + l15 * XP;   // x row (wave 6, qq==2 feeds x)

    float c0 = 0.f, c1 = 0.f;            // cell state for tile 0 / tile 1

    __syncthreads();   // xs + zeros visible

    // ---- seed specials: h1f[0] k=50 = x[m][0]; k=51 = 1.0 in BOTH buffers.
    // The 1.0 lane (wave 6 qq=3) never writes in-loop, so both stay valid.
    if (tid < NB) {
        _Float16* e0 = (_Float16*)&h1f[0][96 + tid];
        e0[2] = (_Float16)xs[tid * XP];
        e0[3] = (_Float16)1.0f;
        ((_Float16*)&h1f[1][96 + tid])[3] = (_Float16)1.0f;
    }
    __syncthreads();

    // ---- phase body: L1-waves do L1[p], L2-waves do L2[p-1]; one barrier ----
    auto phase = [&](const f16x8* __restrict__ h1o, const f16x8* __restrict__ h2o,
                     f16x8* __restrict__ h1n, f16x8* __restrict__ h2n,
                     int p, bool doL1, bool doL2) {
        if (isL1) {
            if (doL1) {
                const f16x8 hb0 = h1o[rdo];
                const f16x8 hb1 = h1o[64 + rdo];
                _Float16 hw[2];
#pragma unroll
                for (int tt = 0; tt < 2; ++tt) {
                    if (tt < nt) {
                        f32x4 acc = {0.f, 0.f, 0.f, 0.f};
                        acc = __builtin_amdgcn_mfma_f32_16x16x32_f16(wA[tt][0], hb0, acc, 0, 0, 0);
                        acc = __builtin_amdgcn_mfma_f32_16x16x32_f16(wA[tt][1], hb1, acc, 0, 0, 0);
                        hw[tt] = (_Float16)lstm_cell(acc, tt ? c1 : c0);
                    }
                }
                if (w < 6) {                           // wave-uniform
                    ((_Float16*)h1n)[wOff[0]] = hw[0];
                    ((_Float16*)h1n)[wOff[1]] = hw[1];
                } else {                               // wave 6: units 48..51
                    if (qq < 2)       ((_Float16*)h1n)[wOff[0]] = hw[0];
                    else if (qq == 2) ((_Float16*)h1n)[wOff[0]] =
                                          (_Float16)xrow[p + 1];
                    /* qq == 3: the 1.0 lane, pre-seeded, never written */
                }
            }
        } else {
            if (doL2) {
                const f16x8 hb0 = h1o[rdo];
                const f16x8 hb1 = h1o[64 + rdo];
                const f16x8 sb0 = h2o[rdo];
                const f16x8 sb1 = h2o[64 + rdo];
#pragma unroll
                for (int tt = 0; tt < 2; ++tt) {
                    if (tt < nt) {
                        f32x4 acc = {0.f, 0.f, 0.f, 0.f};
                        acc = __builtin_amdgcn_mfma_f32_16x16x32_f16(wA[tt][0], hb0, acc, 0, 0, 0);
                        acc = __builtin_amdgcn_mfma_f32_16x16x32_f16(wA[tt][1], hb1, acc, 0, 0, 0);
                        acc = __builtin_amdgcn_mfma_f32_16x16x32_f16(wB[tt][0], sb0, acc, 0, 0, 0);
                        acc = __builtin_amdgcn_mfma_f32_16x16x32_f16(wB[tt][1], sb1, acc, 0, 0, 0);
                        ((_Float16*)h2n)[wOff[tt]] =
                            (_Float16)lstm_cell(acc, tt ? c1 : c0);
                    }
                }
            }
        }
        __syncthreads();
    };

    // phase p reads buf[p&1], writes buf[1-(p&1)]
    phase(h1f[0], h2f[0], h1f[1], h2f[1], 0, true, false);      // L1[0]
#pragma unroll 1
    for (int p = 1; p <= 509; p += 2) {
        phase(h1f[1], h2f[1], h1f[0], h2f[0], p,     true, true);
        phase(h1f[0], h2f[0], h1f[1], h2f[1], p + 1, true, true);
    }
    phase(h1f[1], h2f[1], h1f[0], h2f[0], 511, true,  true);
    phase(h1f[0], h2f[0], h1f[1], h2f[1], 512, false, true);    // L2[511]
    // h2[511] now lives in h2f[1]

    // ============ FC head: out[b] = h2[T-1] . fc_w + fc_b ============
    if (tid < NB) {
        const int m = tid;
        const _Float16* h2e = (const _Float16*)h2f[1];
        float s = fc_b[0];
        for (int j = 0; j < HID; ++j) {
            const int chunk = (((j >> 5) * 4) + ((j >> 3) & 3)) * 16 + m;
            s += fc_w[j] * (float)h2e[chunk * 8 + (j & 7)];
        }
        out[b0 + m] = s;
    }
}

extern "C" void kernel_launch(void* const* d_in, const int* in_sizes, int n_in,
                              void* d_out, int out_size, void* d_ws, size_t ws_size,
                              hipStream_t stream) {
    const float* x     = (const float*)d_in[0];
    const float* w_ih0 = (const float*)d_in[1];
    const float* w_hh0 = (const float*)d_in[2];
    const float* b_ih0 = (const float*)d_in[3];
    const float* b_hh0 = (const float*)d_in[4];
    const float* w_ih1 = (const float*)d_in[5];
    const float* w_hh1 = (const float*)d_in[6];
    const float* b_ih1 = (const float*)d_in[7];
    const float* b_hh1 = (const float*)d_in[8];
    const float* fc_w  = (const float*)d_in[9];
    const float* fc_b  = (const float*)d_in[10];
    float* out = (float*)d_out;

    const int B = in_sizes[0] / SEQ;  // 4096

    lstm2_fc_v11<<<B / NB, NTHREADS, 0, stream>>>(
        x, w_ih0, w_hh0, b_ih0, b_hh0, w_ih1, w_hh1, b_ih1, b_hh1, fc_w, fc_b, out);
}

// Round 12
// 400.419 us; speedup vs baseline: 1.3690x; 1.0557x over previous
//
#include <hip/hip_runtime.h>

// 2-layer LSTM (H=50) + FC head. Transposed-MFMA fp16, cross-layer pipelined.
// R12 = R11 with balanced mixed-role waves + issue-priority on the pacers:
//   waves 0..9  : DUAL role  (L1 tile w + L2 tile w)   6 MFMA + 2 cells, prio 1
//   waves 10..12: single L1 tile w (wave 12 also feeds x into the K-lane)
//   waves 13..15: single L2 tile w-3 (tiles 10..12)
// Same total work as R11 but the per-phase pacer shrinks 8->6 MFMA and
// s_setprio(1) makes heavy waves issue first after each barrier (makespan).
// Core structure (R5/R6/R7): gates^T = W @ h^T, A = weights in registers,
// B = h in LDS fragment layout; gate rows permuted p=4j+g -> one lane owns
// all 4 gates of unit j -> cell update fully in-register; x + biases ride
// dead K-lanes (h1 k=50: x, k=51: 1.0); activations v_rcp+v_exp2;
// phase p = L1[p] + L2[p-1], ONE barrier per phase (513 = minimum).
// Locked-in lessons: NB=16/grid=256 (R8: block work is batch-independent);
// max waves >> fat waves (R10); launch_bounds must not squeeze VGPRs (R3).

#define HID 50
#define SEQ 512
#define NB 16
#define NTHREADS 1024
#define XP 516            // xs row stride (floats)

typedef _Float16 f16x8 __attribute__((ext_vector_type(8)));
typedef float    f32x4 __attribute__((ext_vector_type(4)));

#define LOG2E 1.44269504f

__device__ __forceinline__ float sigf(float x) {
    return __builtin_amdgcn_rcpf(1.0f + __builtin_amdgcn_exp2f(x * -LOG2E));
}
__device__ __forceinline__ float tanh_fast(float x) {
    return 1.0f - 2.0f * __builtin_amdgcn_rcpf(
        1.0f + __builtin_amdgcn_exp2f(x * (2.0f * LOG2E)));
}
__device__ __forceinline__ float lstm_cell(const f32x4 g, float& c) {
    const float ii = sigf(g[0]);
    const float ff = sigf(g[1]);
    const float gg = tanh_fast(g[2]);
    const float oo = sigf(g[3]);
    c = ff * c + ii * gg;
    return oo * tanh_fast(c);
}

// h LDS layout: 16B chunk (kt*4+qh)*16 + m holds h[m][k = kt*32+qh*8+0..7].
// Reader (lane m=l15, quad qq, k-chunk kt) reads chunk (kt*4+qq)*16+m.
// Writer of h[m][j]: chunk ((j>>5)*4+((j>>3)&3))*16 + m, half j&7.
// j=50 -> chunk 96+m half 2 (x rides here), j=51 -> chunk 96+m half 3 (1.0).

__global__ __launch_bounds__(NTHREADS)
void lstm2_fc_v12(const float* __restrict__ x,
                  const float* __restrict__ w_ih0,
                  const float* __restrict__ w_hh0,
                  const float* __restrict__ b_ih0,
                  const float* __restrict__ b_hh0,
                  const float* __restrict__ w_ih1,
                  const float* __restrict__ w_hh1,
                  const float* __restrict__ b_ih1,
                  const float* __restrict__ b_hh1,
                  const float* __restrict__ fc_w,
                  const float* __restrict__ fc_b,
                  float* __restrict__ out)
{
    __shared__ float xs[NB * XP];        // 33 KB  x for all 512 steps
    __shared__ f16x8 h1f[2][128];        //  4 KB  h1 double-buffered, frag layout
    __shared__ f16x8 h2f[2][128];        //  4 KB  h2 double-buffered

    const int tid = threadIdx.x;
    const int b0  = blockIdx.x * NB;
    const int w   = tid >> 6;            // wave id 0..15
    const int l15 = tid & 15;            // MFMA lane column (batch m)
    const int qq  = (tid >> 4) & 3;      // MFMA lane quad

    // ---- role assignment (wave-uniform) ----
    const bool dual  = (w <= 9);
    const bool hasL1 = (w <= 12);
    const bool hasL2 = dual || (w >= 13);
    const int  tL1   = w;                        // L1 tile (if hasL1)
    const int  tL2   = dual ? w : (w - 3);       // L2 tile (if hasL2)

    if (dual) __builtin_amdgcn_s_setprio(1);     // pacers issue first post-barrier

    // ---- stage x into LDS (coalesced float4) ----
    for (int idx = tid; idx < NB * 128; idx += NTHREADS) {
        const int b  = idx >> 7;
        const int t4 = idx & 127;
        *(float4*)&xs[b * XP + t4 * 4] =
            *(const float4*)&x[(size_t)(b0 + b) * SEQ + t4 * 4];
    }
    if (tid < NB) {                       // zero x pad column t=512..515
        const float4 z = {0.f, 0.f, 0.f, 0.f};
        *(float4*)&xs[tid * XP + 512] = z;
    }
    // ---- zero h buffers ----
    if (tid < 256) {
        f16x8 z = {};
        h1f[tid >> 7][tid & 127] = z;
        h2f[tid >> 7][tid & 127] = z;
    }

    // ---- load weight A-fragments (one-time), gate rows permuted ----
    // lane holds W[p = T*16 + l15][k = kt*32 + qq*8 + j], n(p)=(p&3)*HID+(p>>2)
    // L1 frag (w_hh0): specials k=50 -> w_ih0, k=51 -> biasL1.
    // L2 frags: w_ih1 (special k=51 -> biasL2) and w_hh1.
    f16x8 wH0[2], wI1[2], wH1[2];
    {
        const int  p1  = tL1 * 16 + l15;
        const bool ok1 = hasL1 && (p1 < 4 * HID);
        const int  n1  = ok1 ? ((p1 & 3) * HID + (p1 >> 2)) : 0;
        const int  p2  = tL2 * 16 + l15;
        const bool ok2 = hasL2 && (p2 < 4 * HID);
        const int  n2  = ok2 ? ((p2 & 3) * HID + (p2 >> 2)) : 0;
#pragma unroll
        for (int kt = 0; kt < 2; ++kt) {
            f16x8 f0, f1, f2;
#pragma unroll
            for (int j = 0; j < 8; ++j) {
                const int k = kt * 32 + qq * 8 + j;
                float v0 = 0.0f, v1 = 0.0f, v2 = 0.0f;
                if (ok1) {
                    if (k < HID)          v0 = w_hh0[n1 * HID + k];
                    else if (k == HID)    v0 = w_ih0[n1];
                    else if (k == HID+1)  v0 = b_ih0[n1] + b_hh0[n1];
                }
                if (ok2) {
                    if (k < HID)        { v1 = w_ih1[n2 * HID + k];
                                          v2 = w_hh1[n2 * HID + k]; }
                    else if (k == HID+1)  v1 = b_ih1[n2] + b_hh1[n2];
                }
                f0[j] = (_Float16)v0;
                f1[j] = (_Float16)v1;
                f2[j] = (_Float16)v2;
            }
            wH0[kt] = f0;
            wI1[kt] = f1;
            wH1[kt] = f2;
        }
    }

    // ---- per-lane invariants ----
    const int juL1   = tL1 * 4 + qq;             // unit of my L1 tile (<=51)
    const int juL2   = tL2 * 4 + qq;
    const int wOffL1 = ((((juL1 >> 5) * 4) + ((juL1 >> 3) & 3)) * 16 + l15) * 8 + (juL1 & 7);
    const int wOffL2 = ((((juL2 >> 5) * 4) + ((juL2 >> 3) & 3)) * 16 + l15) * 8 + (juL2 & 7);
    const int rdo = qq * 16 + l15;               // B-frag chunk index, kt=0
    const float* xrow = xs + l15 * XP;           // x row (wave 12, qq==2 feeds x)
    const f32x4 z4 = {0.f, 0.f, 0.f, 0.f};       // hoisted zero accumulator

    float c1 = 0.f, c2 = 0.f;

    __syncthreads();   // xs + zeros visible

    // ---- seed specials: h1f[0] k=50 = x[m][0]; k=51 = 1.0 in BOTH buffers.
    // The 1.0 lane (wave 12 qq=3) never writes in-loop, so both stay valid.
    if (tid < NB) {
        _Float16* e0 = (_Float16*)&h1f[0][96 + tid];
        e0[2] = (_Float16)xs[tid * XP];
        e0[3] = (_Float16)1.0f;
        ((_Float16*)&h1f[1][96 + tid])[3] = (_Float16)1.0f;
    }
    __syncthreads();

    // ---- phase body: L1-part [p], L2-part [p-1]; one barrier ----
    auto phase = [&](const f16x8* __restrict__ h1o, const f16x8* __restrict__ h2o,
                     f16x8* __restrict__ h1n, f16x8* __restrict__ h2n,
                     int p, bool doL1, bool doL2) {
        const f16x8 hb0 = h1o[rdo];              // shared by L1 and L2 parts
        const f16x8 hb1 = h1o[64 + rdo];
        if (hasL2 && doL2) {
            const f16x8 sb0 = h2o[rdo];
            const f16x8 sb1 = h2o[64 + rdo];
            f32x4 acc;
            acc = __builtin_amdgcn_mfma_f32_16x16x32_f16(wI1[0], hb0, z4,  0, 0, 0);
            acc = __builtin_amdgcn_mfma_f32_16x16x32_f16(wI1[1], hb1, acc, 0, 0, 0);
            acc = __builtin_amdgcn_mfma_f32_16x16x32_f16(wH1[0], sb0, acc, 0, 0, 0);
            acc = __builtin_amdgcn_mfma_f32_16x16x32_f16(wH1[1], sb1, acc, 0, 0, 0);
            ((_Float16*)h2n)[wOffL2] = (_Float16)lstm_cell(acc, c2);
        }
        if (hasL1 && doL1) {
            f32x4 acc;
            acc = __builtin_amdgcn_mfma_f32_16x16x32_f16(wH0[0], hb0, z4,  0, 0, 0);
            acc = __builtin_amdgcn_mfma_f32_16x16x32_f16(wH0[1], hb1, acc, 0, 0, 0);
            const _Float16 hw = (_Float16)lstm_cell(acc, c1);
            if (w < 12) {                          // wave-uniform
                ((_Float16*)h1n)[wOffL1] = hw;
            } else {                               // wave 12: units 48..51
                if (qq < 2)       ((_Float16*)h1n)[wOffL1] = hw;
                else if (qq == 2) ((_Float16*)h1n)[wOffL1] =
                                      (_Float16)xrow[p + 1];
                /* qq == 3: the 1.0 lane, pre-seeded, never written */
            }
        }
        __syncthreads();
    };

    // phase p reads buf[p&1], writes buf[1-(p&1)]
    phase(h1f[0], h2f[0], h1f[1], h2f[1], 0, true, false);      // L1[0]
#pragma unroll 1
    for (int p = 1; p <= 509; p += 2) {
        phase(h1f[1], h2f[1], h1f[0], h2f[0], p,     true, true);
        phase(h1f[0], h2f[0], h1f[1], h2f[1], p + 1, true, true);
    }
    phase(h1f[1], h2f[1], h1f[0], h2f[0], 511, true,  true);
    phase(h1f[0], h2f[0], h1f[1], h2f[1], 512, false, true);    // L2[511]
    // h2[511] now lives in h2f[1]

    // ============ FC head: out[b] = h2[T-1] . fc_w + fc_b ============
    if (tid < NB) {
        const int m = tid;
        const _Float16* h2e = (const _Float16*)h2f[1];
        float s = fc_b[0];
        for (int j = 0; j < HID; ++j) {
            const int chunk = (((j >> 5) * 4) + ((j >> 3) & 3)) * 16 + m;
            s += fc_w[j] * (float)h2e[chunk * 8 + (j & 7)];
        }
        out[b0 + m] = s;
    }
}

extern "C" void kernel_launch(void* const* d_in, const int* in_sizes, int n_in,
                              void* d_out, int out_size, void* d_ws, size_t ws_size,
                              hipStream_t stream) {
    const float* x     = (const float*)d_in[0];
    const float* w_ih0 = (const float*)d_in[1];
    const float* w_hh0 = (const float*)d_in[2];
    const float* b_ih0 = (const float*)d_in[3];
    const float* b_hh0 = (const float*)d_in[4];
    const float* w_ih1 = (const float*)d_in[5];
    const float* w_hh1 = (const float*)d_in[6];
    const float* b_ih1 = (const float*)d_in[7];
    const float* b_hh1 = (const float*)d_in[8];
    const float* fc_w  = (const float*)d_in[9];
    const float* fc_b  = (const float*)d_in[10];
    float* out = (float*)d_out;

    const int B = in_sizes[0] / SEQ;  // 4096

    lstm2_fc_v12<<<B / NB, NTHREADS, 0, stream>>>(
        x, w_ih0, w_hh0, b_ih0, b_hh0, w_ih1, w_hh1, b_ih1, b_hh1, fc_w, fc_b, out);
}

// Round 13
// 383.983 us; speedup vs baseline: 1.4276x; 1.0428x over previous
//
#include <hip/hip_runtime.h>

// 2-layer LSTM (H=50) + FC head. Transposed-MFMA fp16, cross-layer pipelined.
// R13 = R12 + activation scale factors FOLDED INTO THE WEIGHTS:
//   gate rows are pre-scaled at fragment-load: i/f/o rows by -log2e, g rows
//   by +2log2e (including their bias and x K-lane entries), so the MFMA
//   output is directly the exp2 argument: sigmoid = rcp(1+exp2(g)),
//   tanh_gate = 1-2*rcp(1+exp2(g)). Kills 4 v_mul per cell, all on the
//   MFMA->trans dependency chain. Only tanh(c) keeps its scale mul.
// Wave roles (R12): 0..9 dual (L1 tile w + L2 tile w, prio 1), 10..12 L1
// single (12 feeds x), 13..15 L2 single (tiles 10..12).
// Core: gates^T = W @ h^T; A = weights in regs, B = h in LDS frag layout;
// gate rows permuted p=4j+g -> one lane owns a unit's 4 gates -> cell fully
// in-register; x + biases ride dead K-lanes (h1 k=50: x, k=51: 1.0);
// phase p = L1[p] + L2[p-1], ONE barrier/phase (513 = minimum).
// Lessons: NB=16/grid=256 locked (R8); max waves > fat waves (R10); no
// VGPR-squeezing launch_bounds (R3).

#define HID 50
#define SEQ 512
#define NB 16
#define NTHREADS 1024
#define XP 516            // xs row stride (floats)

typedef _Float16 f16x8 __attribute__((ext_vector_type(8)));
typedef float    f32x4 __attribute__((ext_vector_type(4)));

#define LOG2E 1.44269504f

// pre-scaled activations: input is already  -x*log2e  (sig) or  2x*log2e (tanh)
__device__ __forceinline__ float sig_pre(float y) {
    return __builtin_amdgcn_rcpf(1.0f + __builtin_amdgcn_exp2f(y));
}
__device__ __forceinline__ float tanh_pre(float y) {
    return 1.0f - 2.0f * __builtin_amdgcn_rcpf(1.0f + __builtin_amdgcn_exp2f(y));
}
// c is unscaled -> needs the mul
__device__ __forceinline__ float tanh_c(float x) {
    return 1.0f - 2.0f * __builtin_amdgcn_rcpf(
        1.0f + __builtin_amdgcn_exp2f(x * (2.0f * LOG2E)));
}
__device__ __forceinline__ float lstm_cell(const f32x4 g, float& c) {
    const float ii = sig_pre(g[0]);
    const float ff = sig_pre(g[1]);
    const float gg = tanh_pre(g[2]);
    const float oo = sig_pre(g[3]);
    c = ff * c + ii * gg;
    return oo * tanh_c(c);
}

// h LDS layout: 16B chunk (kt*4+qh)*16 + m holds h[m][k = kt*32+qh*8+0..7].
// Reader (lane m=l15, quad qq, k-chunk kt) reads chunk (kt*4+qq)*16+m.
// Writer of h[m][j]: chunk ((j>>5)*4+((j>>3)&3))*16 + m, half j&7.
// j=50 -> chunk 96+m half 2 (x rides here), j=51 -> chunk 96+m half 3 (1.0).

__global__ __launch_bounds__(NTHREADS)
void lstm2_fc_v13(const float* __restrict__ x,
                  const float* __restrict__ w_ih0,
                  const float* __restrict__ w_hh0,
                  const float* __restrict__ b_ih0,
                  const float* __restrict__ b_hh0,
                  const float* __restrict__ w_ih1,
                  const float* __restrict__ w_hh1,
                  const float* __restrict__ b_ih1,
                  const float* __restrict__ b_hh1,
                  const float* __restrict__ fc_w,
                  const float* __restrict__ fc_b,
                  float* __restrict__ out)
{
    __shared__ float xs[NB * XP];        // 33 KB  x for all 512 steps
    __shared__ f16x8 h1f[2][128];        //  4 KB  h1 double-buffered, frag layout
    __shared__ f16x8 h2f[2][128];        //  4 KB  h2 double-buffered

    const int tid = threadIdx.x;
    const int b0  = blockIdx.x * NB;
    const int w   = tid >> 6;            // wave id 0..15
    const int l15 = tid & 15;            // MFMA lane column (batch m)
    const int qq  = (tid >> 4) & 3;      // MFMA lane quad

    // ---- role assignment (wave-uniform) ----
    const bool dual  = (w <= 9);
    const bool hasL1 = (w <= 12);
    const bool hasL2 = dual || (w >= 13);
    const int  tL1   = w;                        // L1 tile (if hasL1)
    const int  tL2   = dual ? w : (w - 3);       // L2 tile (if hasL2)

    if (dual) __builtin_amdgcn_s_setprio(1);     // pacers issue first post-barrier

    // ---- stage x into LDS (coalesced float4) ----
    for (int idx = tid; idx < NB * 128; idx += NTHREADS) {
        const int b  = idx >> 7;
        const int t4 = idx & 127;
        *(float4*)&xs[b * XP + t4 * 4] =
            *(const float4*)&x[(size_t)(b0 + b) * SEQ + t4 * 4];
    }
    if (tid < NB) {                       // zero x pad column t=512..515
        const float4 z = {0.f, 0.f, 0.f, 0.f};
        *(float4*)&xs[tid * XP + 512] = z;
    }
    // ---- zero h buffers ----
    if (tid < 256) {
        f16x8 z = {};
        h1f[tid >> 7][tid & 127] = z;
        h2f[tid >> 7][tid & 127] = z;
    }

    // ---- load weight A-fragments (one-time), gate rows permuted + SCALED ----
    // lane holds W[p = T*16 + l15][k = kt*32 + qq*8 + j], n(p)=(p&3)*HID+(p>>2)
    // row scale: gate (p&3)==2 (tanh) -> +2log2e, else (sigmoid) -> -log2e.
    // L1 frag (w_hh0): specials k=50 -> w_ih0, k=51 -> biasL1 (both scaled).
    // L2 frags: w_ih1 (special k=51 -> biasL2, scaled) and w_hh1.
    f16x8 wH0[2], wI1[2], wH1[2];
    {
        const int  p1  = tL1 * 16 + l15;
        const bool ok1 = hasL1 && (p1 < 4 * HID);
        const int  n1  = ok1 ? ((p1 & 3) * HID + (p1 >> 2)) : 0;
        const float s1 = ((p1 & 3) == 2) ? (2.0f * LOG2E) : -LOG2E;
        const int  p2  = tL2 * 16 + l15;
        const bool ok2 = hasL2 && (p2 < 4 * HID);
        const int  n2  = ok2 ? ((p2 & 3) * HID + (p2 >> 2)) : 0;
        const float s2 = ((p2 & 3) == 2) ? (2.0f * LOG2E) : -LOG2E;
#pragma unroll
        for (int kt = 0; kt < 2; ++kt) {
            f16x8 f0, f1, f2;
#pragma unroll
            for (int j = 0; j < 8; ++j) {
                const int k = kt * 32 + qq * 8 + j;
                float v0 = 0.0f, v1 = 0.0f, v2 = 0.0f;
                if (ok1) {
                    if (k < HID)          v0 = w_hh0[n1 * HID + k];
                    else if (k == HID)    v0 = w_ih0[n1];
                    else if (k == HID+1)  v0 = b_ih0[n1] + b_hh0[n1];
                    v0 *= s1;
                }
                if (ok2) {
                    if (k < HID)        { v1 = w_ih1[n2 * HID + k];
                                          v2 = w_hh1[n2 * HID + k]; }
                    else if (k == HID+1)  v1 = b_ih1[n2] + b_hh1[n2];
                    v1 *= s2;
                    v2 *= s2;
                }
                f0[j] = (_Float16)v0;
                f1[j] = (_Float16)v1;
                f2[j] = (_Float16)v2;
            }
            wH0[kt] = f0;
            wI1[kt] = f1;
            wH1[kt] = f2;
        }
    }

    // ---- per-lane invariants ----
    const int juL1   = tL1 * 4 + qq;             // unit of my L1 tile (<=51)
    const int juL2   = tL2 * 4 + qq;
    const int wOffL1 = ((((juL1 >> 5) * 4) + ((juL1 >> 3) & 3)) * 16 + l15) * 8 + (juL1 & 7);
    const int wOffL2 = ((((juL2 >> 5) * 4) + ((juL2 >> 3) & 3)) * 16 + l15) * 8 + (juL2 & 7);
    const int rdo = qq * 16 + l15;               // B-frag chunk index, kt=0
    const float* xrow = xs + l15 * XP;           // x row (wave 12, qq==2 feeds x)
    const f32x4 z4 = {0.f, 0.f, 0.f, 0.f};       // hoisted zero accumulator

    float c1 = 0.f, c2 = 0.f;

    __syncthreads();   // xs + zeros visible

    // ---- seed specials: h1f[0] k=50 = x[m][0]; k=51 = 1.0 in BOTH buffers.
    // The 1.0 lane (wave 12 qq=3) never writes in-loop, so both stay valid.
    if (tid < NB) {
        _Float16* e0 = (_Float16*)&h1f[0][96 + tid];
        e0[2] = (_Float16)xs[tid * XP];
        e0[3] = (_Float16)1.0f;
        ((_Float16*)&h1f[1][96 + tid])[3] = (_Float16)1.0f;
    }
    __syncthreads();

    // ---- phase body: L1-part [p], L2-part [p-1]; one barrier ----
    auto phase = [&](const f16x8* __restrict__ h1o, const f16x8* __restrict__ h2o,
                     f16x8* __restrict__ h1n, f16x8* __restrict__ h2n,
                     int p, bool doL1, bool doL2) {
        const f16x8 hb0 = h1o[rdo];              // shared by L1 and L2 parts
        const f16x8 hb1 = h1o[64 + rdo];
        if (hasL2 && doL2) {
            const f16x8 sb0 = h2o[rdo];
            const f16x8 sb1 = h2o[64 + rdo];
            f32x4 acc;
            acc = __builtin_amdgcn_mfma_f32_16x16x32_f16(wI1[0], hb0, z4,  0, 0, 0);
            acc = __builtin_amdgcn_mfma_f32_16x16x32_f16(wI1[1], hb1, acc, 0, 0, 0);
            acc = __builtin_amdgcn_mfma_f32_16x16x32_f16(wH1[0], sb0, acc, 0, 0, 0);
            acc = __builtin_amdgcn_mfma_f32_16x16x32_f16(wH1[1], sb1, acc, 0, 0, 0);
            ((_Float16*)h2n)[wOffL2] = (_Float16)lstm_cell(acc, c2);
        }
        if (hasL1 && doL1) {
            f32x4 acc;
            acc = __builtin_amdgcn_mfma_f32_16x16x32_f16(wH0[0], hb0, z4,  0, 0, 0);
            acc = __builtin_amdgcn_mfma_f32_16x16x32_f16(wH0[1], hb1, acc, 0, 0, 0);
            const _Float16 hw = (_Float16)lstm_cell(acc, c1);
            if (w < 12) {                          // wave-uniform
                ((_Float16*)h1n)[wOffL1] = hw;
            } else {                               // wave 12: units 48..51
                if (qq < 2)       ((_Float16*)h1n)[wOffL1] = hw;
                else if (qq == 2) ((_Float16*)h1n)[wOffL1] =
                                      (_Float16)xrow[p + 1];
                /* qq == 3: the 1.0 lane, pre-seeded, never written */
            }
        }
        __syncthreads();
    };

    // phase p reads buf[p&1], writes buf[1-(p&1)]
    phase(h1f[0], h2f[0], h1f[1], h2f[1], 0, true, false);      // L1[0]
#pragma unroll 1
    for (int p = 1; p <= 509; p += 2) {
        phase(h1f[1], h2f[1], h1f[0], h2f[0], p,     true, true);
        phase(h1f[0], h2f[0], h1f[1], h2f[1], p + 1, true, true);
    }
    phase(h1f[1], h2f[1], h1f[0], h2f[0], 511, true,  true);
    phase(h1f[0], h2f[0], h1f[1], h2f[1], 512, false, true);    // L2[511]
    // h2[511] now lives in h2f[1]

    // ============ FC head: out[b] = h2[T-1] . fc_w + fc_b ============
    if (tid < NB) {
        const int m = tid;
        const _Float16* h2e = (const _Float16*)h2f[1];
        float s = fc_b[0];
        for (int j = 0; j < HID; ++j) {
            const int chunk = (((j >> 5) * 4) + ((j >> 3) & 3)) * 16 + m;
            s += fc_w[j] * (float)h2e[chunk * 8 + (j & 7)];
        }
        out[b0 + m] = s;
    }
}

extern "C" void kernel_launch(void* const* d_in, const int* in_sizes, int n_in,
                              void* d_out, int out_size, void* d_ws, size_t ws_size,
                              hipStream_t stream) {
    const float* x     = (const float*)d_in[0];
    const float* w_ih0 = (const float*)d_in[1];
    const float* w_hh0 = (const float*)d_in[2];
    const float* b_ih0 = (const float*)d_in[3];
    const float* b_hh0 = (const float*)d_in[4];
    const float* w_ih1 = (const float*)d_in[5];
    const float* w_hh1 = (const float*)d_in[6];
    const float* b_ih1 = (const float*)d_in[7];
    const float* b_hh1 = (const float*)d_in[8];
    const float* fc_w  = (const float*)d_in[9];
    const float* fc_b  = (const float*)d_in[10];
    float* out = (float*)d_out;

    const int B = in_sizes[0] / SEQ;  // 4096

    lstm2_fc_v13<<<B / NB, NTHREADS, 0, stream>>>(
        x, w_ih0, w_hh0, b_ih0, b_hh0, w_ih1, w_hh1, b_ih1, b_hh1, fc_w, fc_b, out);
}